// Round 3
// baseline (508.675 us; speedup 1.0000x reference)
//
#include <hip/hip_runtime.h>

// Problem constants: B=4, L=4096, C=1024, H=16, W=512, D=64, STRIDE=256
// Only windows 0..7 reach the output; q/k/v needed only for rows [0,2304) per batch.
#define LQ 2304

typedef __attribute__((ext_vector_type(8))) short bf16x8;
typedef __attribute__((ext_vector_type(8))) unsigned short u16x8;
typedef __attribute__((ext_vector_type(4))) unsigned short u16x4;
typedef __attribute__((ext_vector_type(4))) float f32x4;
typedef __attribute__((ext_vector_type(4))) unsigned int u32x4;

#define MFMA(a, b, c) __builtin_amdgcn_mfma_f32_16x16x32_bf16((a), (b), (c), 0, 0, 0)
#define AS1 __attribute__((address_space(1)))
#define AS3 __attribute__((address_space(3)))

static __device__ __forceinline__ unsigned short f2bf(float f) {
  unsigned int u = __builtin_bit_cast(unsigned int, f);
  u += 0x7fffu + ((u >> 16) & 1u);
  return (unsigned short)(u >> 16);
}

// pack two positive f32 into bf16x2 by byte-perm truncation (caller pre-biases)
static __device__ __forceinline__ unsigned int pkbf(float hi, float lo) {
  return __builtin_amdgcn_perm(__builtin_bit_cast(unsigned int, hi),
                               __builtin_bit_cast(unsigned int, lo), 0x07060302u);
}

// async 16B/lane global->LDS; LDS image is wave-uniform base + lane*16 (no padding!)
static __device__ __forceinline__ void lds16(const unsigned short* g, unsigned short* l) {
  __builtin_amdgcn_global_load_lds((AS1 const unsigned int*)g, (AS3 unsigned int*)l, 16, 0, 0);
}

// ---------------- fused preprocessing: x fp32->bf16 + both weight transposes
// blocks [0,4608): conv_x; [4608,7680): w_qkv^T; [7680,8704): w_out^T
static __device__ __forceinline__ void transpose_body(const float* __restrict__ src,
                                                      unsigned short* __restrict__ dst,
                                                      int K, int N, int bx, int by, int tid,
                                                      float (*t)[33]) {
  int bn = bx * 32, bk = by * 32;
  int tx = tid & 31, ty = tid >> 5;
  for (int i = ty; i < 32; i += 8)
    t[i][tx] = src[(size_t)(bk + i) * N + bn + tx];
  __syncthreads();
  for (int i = ty; i < 32; i += 8)
    dst[(size_t)(bn + i) * K + bk + tx] = f2bf(t[tx][i]);
}

__global__ __launch_bounds__(256) void preprocess(const float* __restrict__ x,
                                                  unsigned short* __restrict__ xbf,
                                                  const float* __restrict__ wqkv,
                                                  unsigned short* __restrict__ wqkvT,
                                                  const float* __restrict__ wout,
                                                  unsigned short* __restrict__ woutT) {
  __shared__ float t[32][33];
  int bid = blockIdx.x, tid = threadIdx.x;
  if (bid < 4608) {
    int idx = bid * 256 + tid;          // [0, 1179648)
    int b = idx / 294912;               // 294912 = 2304*128
    int g = idx - b * 294912;
    int row = g >> 7, c8 = (g & 127) * 8;
    const float* src = x + ((size_t)b * 4096 + row) * 1024 + c8;
    float4 f0 = *(const float4*)src;
    float4 f1 = *(const float4*)(src + 4);
    u16x8 u;
    u[0] = f2bf(f0.x); u[1] = f2bf(f0.y); u[2] = f2bf(f0.z); u[3] = f2bf(f0.w);
    u[4] = f2bf(f1.x); u[5] = f2bf(f1.y); u[6] = f2bf(f1.z); u[7] = f2bf(f1.w);
    *(u16x8*)(xbf + ((size_t)b * 2304 + row) * 1024 + c8) = u;
  } else if (bid < 7680) {
    int tb = bid - 4608;
    transpose_body(wqkv, wqkvT, 1024, 3072, tb % 96, tb / 96, tid, t);
  } else {
    int tb = bid - 7680;
    transpose_body(wout, woutT, 1024, 1024, tb & 31, tb >> 5, tid, t);
  }
}

// ---------------- QKV projection GEMM: tile 128x128, BK=64, 256 threads = 2x2 waves.
// V is written TRANSPOSED + key-permuted: vT[(b,h,d,key')] with
// key' = (key&~31) | (q<<3) | (t<<2) | (key&3) for key = 32c+16t+4q+r.
// This is exactly the in-LDS permutation the attention PV step needs, so the attn
// kernel can stage V with global_load_lds (linear LDS image, pre-swizzled source).
#define K2SCALE 0.18033688011112042f
__global__ __launch_bounds__(256) void qkv_gemm(const unsigned short* __restrict__ xbf,
                                                const float* __restrict__ bqkv,
                                                const unsigned short* __restrict__ wT,
                                                unsigned short* __restrict__ qws,
                                                unsigned short* __restrict__ kws,
                                                unsigned short* __restrict__ vws) {
  __shared__ __align__(16) unsigned short As[128 * 64];
  __shared__ __align__(16) unsigned short Bs[128 * 64];
  const int tid = threadIdx.x;
  const int mt = blockIdx.y;            // 0..71 : batch*18 + row-tile
  const int nt = blockIdx.x;            // 0..23
  const int bidx = mt / 18;
  const int l0 = (mt % 18) * 128;
  const int n0 = nt * 128;
  const int lane = tid & 63, wv = tid >> 6;
  const int wm = (wv >> 1) * 64, wn = (wv & 1) * 64;
  const int l16 = lane & 15, quad = lane >> 4;

  const int srow = lane >> 3;                 // 0..7
  const int sc = ((lane & 7) ^ srow) * 8;     // swizzled 16B chunk within the row
  const unsigned short* ga = xbf + ((size_t)(bidx * LQ + l0 + wv * 32 + srow)) * 1024 + sc;
  const unsigned short* gb = wT + ((size_t)(n0 + wv * 32 + srow)) * 1024 + sc;
  unsigned short* la = As + wv * 2048;
  unsigned short* lb = Bs + wv * 2048;
  const int xsw = (l16 & 7) * 8;              // reader-side swizzle key (row&7)*8

  const f32x4 zero4 = {0.f, 0.f, 0.f, 0.f};
  f32x4 acc[4][4];
#pragma unroll
  for (int i = 0; i < 4; i++)
#pragma unroll
    for (int j = 0; j < 4; j++) acc[i][j] = zero4;

  for (int k0 = 0; k0 < 1024; k0 += 64) {
    __syncthreads();
#pragma unroll
    for (int j = 0; j < 4; j++) {
      lds16(ga + j * 8 * 1024, la + j * 512);
      lds16(gb + j * 8 * 1024, lb + j * 512);
    }
    __syncthreads();
#pragma unroll
    for (int h = 0; h < 2; h++) {
      bf16x8 af[4], bfv[4];
#pragma unroll
      for (int i = 0; i < 4; i++)
        af[i] = *(const bf16x8*)(&As[(wm + i * 16 + l16) * 64 + (((h << 5) + quad * 8) ^ xsw)]);
#pragma unroll
      for (int j = 0; j < 4; j++)
        bfv[j] = *(const bf16x8*)(&Bs[(wn + j * 16 + l16) * 64 + (((h << 5) + quad * 8) ^ xsw)]);
#pragma unroll
      for (int i = 0; i < 4; i++)
#pragma unroll
        for (int j = 0; j < 4; j++)
          acc[i][j] = MFMA(af[i], bfv[j], acc[i][j]);
    }
    ga += 64;
    gb += 64;
  }

  // epilogue: scatter to q/k (B,H,LQ,64) with bias; q pre-scaled by K2SCALE;
  // v goes out transposed+permuted (B,H,64,LQ') with 8B packed stores.
#pragma unroll
  for (int j = 0; j < 4; j++) {
    int col = n0 + wn + j * 16 + l16;   // [0,3072)
    int which = col >> 10;              // wave-uniform
    int hcol = (col >> 6) & 15;
    int dcol = col & 63;
    float bias = bqkv[col];
    if (which == 2) {
      size_t vbase = (((size_t)bidx * 16 + hcol) * 64 + dcol) * (size_t)LQ;
#pragma unroll
      for (int i = 0; i < 4; i++) {
        int lrow = l0 + wm + i * 16 + quad * 4;   // bits[1:0] == 0
        int pbase = (lrow & ~31) | (((lrow >> 2) & 3) << 3) | (((lrow >> 4) & 1) << 2);
        u16x4 st;
#pragma unroll
        for (int r = 0; r < 4; r++) st[r] = f2bf(acc[i][j][r] + bias);
        *(u16x4*)(vws + vbase + pbase) = st;
      }
    } else {
      unsigned short* dst = which == 0 ? qws : kws;
      float scale = which == 0 ? K2SCALE : 1.0f;
      size_t cbase = ((size_t)bidx * 16 + hcol) * ((size_t)LQ * 64) + dcol;
#pragma unroll
      for (int i = 0; i < 4; i++) {
        int lrow = l0 + wm + i * 16 + quad * 4;
#pragma unroll
        for (int r = 0; r < 4; r++)
          dst[cbase + (size_t)(lrow + r) * 64] = f2bf((acc[i][j][r] + bias) * scale);
      }
    }
  }
}

// ---------------- attention: one block per (head/batch hb, window n)
// grid.x = h + 16*b so all 8 windows of one (b,h) share an XCD (k/v overlap -> L2).
// Double-buffered LDS (2x16KB K + 2x16KB V = 64KB, 2 blocks/CU via LDS limit)
// staged entirely by global_load_lds width-16: issue tile kt+1's DMA BEFORE
// computing tile kt, one barrier per iteration (T3 minimum-2-phase). LDS images
// are linear with the 16B chunk XOR swizzle (chunk ^= row&7) pre-applied to the
// per-lane GLOBAL source address, so every ds_read_b128 below is at the 8-way
// bank minimum. Epilogue transposes O through LDS and stores u16x8 (full 128B
// lines) to kill the 4x partial-line write amplification of 2B scatter stores.
__global__ __launch_bounds__(512, 2) void attn_kernel(const unsigned short* __restrict__ q,
                                                      const unsigned short* __restrict__ k,
                                                      const unsigned short* __restrict__ vT,
                                                      unsigned short* __restrict__ o) {
  __shared__ __align__(16) unsigned short Ks[2 * 8192];   // [sel][key 128][d 64] swizzled
  __shared__ __align__(16) unsigned short Vt[2 * 8192];   // [sel][d 64][key' 128] swizzled
  const int hb = blockIdx.x, n = blockIdx.y;
  const int h = hb & 15, b = hb >> 4;
  const size_t base = (((size_t)b * 16 + h) * LQ + n * 256) * 64;
  const unsigned short* qg = q + base;
  const unsigned short* kg = k + base;
  const unsigned short* vg = vT + ((size_t)b * 16 + h) * 64 * (size_t)LQ + n * 256;
  const int tid = threadIdx.x;
  const int lane = tid & 63, wv = tid >> 6;
  const int l16 = lane & 15, quad = lane >> 4;
  const int h7 = l16 & 7;
  const f32x4 zero4 = {0.f, 0.f, 0.f, 0.f};
  const float RB = 0.002815015607053277f;  // log2(1 + 2^-9): centers perm-truncation

  // per-lane staging sources (tile 0); later tiles offset by +128 rows (K) /
  // +128 key' cols (V), which preserve row&7 so the XOR swizzle key is identical.
  const int skey = tid >> 3;                  // K: 8 lanes per key row (8 chunks)
  const unsigned short* ks0 = kg + (size_t)skey * 64 + (((tid & 7) ^ (skey & 7)) * 8);
  const int sd = tid >> 4;                    // V: 16 lanes per d row (16 chunks)
  const unsigned short* vs0 = vg + (size_t)sd * LQ + (((tid & 15) ^ (sd & 7)) * 8);
  unsigned short* kl = Ks + wv * 512;         // wave-uniform LDS bases (lane*16 implicit)
  unsigned short* vl = Vt + wv * 512;

#define STAGE(t, sel)                                          \
  do {                                                         \
    lds16(ks0 + (t) * 8192, kl + (sel) * 8192);                \
    lds16(ks0 + (t) * 8192 + 4096, kl + (sel) * 8192 + 4096);  \
    lds16(vs0 + (t) * 128, vl + (sel) * 8192);                 \
    lds16(vs0 + (t) * 128 + (size_t)32 * LQ, vl + (sel) * 8192 + 4096); \
  } while (0)

  bf16x8 qf0[4], qf1[4];
#pragma unroll
  for (int qs = 0; qs < 4; qs++) {
    int qrow = wv * 64 + qs * 16 + l16;
    qf0[qs] = *(const bf16x8*)(qg + (size_t)qrow * 64 + quad * 8);
    qf1[qs] = *(const bf16x8*)(qg + (size_t)qrow * 64 + quad * 8 + 32);
  }
  f32x4 O[4][4];
#pragma unroll
  for (int qs = 0; qs < 4; qs++)
#pragma unroll
    for (int dt = 0; dt < 4; dt++) O[qs][dt] = zero4;
  float lsum[4] = {0.f, 0.f, 0.f, 0.f};

  STAGE(0, 0);
  __syncthreads();                       // drains vmcnt(0): tile 0 resident

#pragma unroll
  for (int kt = 0; kt < 4; kt++) {
    const int sel = kt & 1;
    if (kt < 3) STAGE(kt + 1, sel ^ 1);  // in flight across the whole compute phase
    const unsigned short* Kb = Ks + sel * 8192;
    const unsigned short* Vb = Vt + sel * 8192;
    for (int c = 0; c < 4; c++) {
      const int ra = (c * 32 + l16) * 64;
      bf16x8 ka0 = *(const bf16x8*)(Kb + ra + ((quad ^ h7) * 8));
      bf16x8 ka1 = *(const bf16x8*)(Kb + ra + (((quad + 4) ^ h7) * 8));
      bf16x8 kb0 = *(const bf16x8*)(Kb + ra + 1024 + ((quad ^ h7) * 8));
      bf16x8 kb1 = *(const bf16x8*)(Kb + ra + 1024 + (((quad + 4) ^ h7) * 8));
      bf16x8 vf[4];
#pragma unroll
      for (int dt = 0; dt < 4; dt++)
        vf[dt] = *(const bf16x8*)(Vb + (dt * 16 + l16) * 128 + (((c * 4 + quad) ^ h7) * 8));
#pragma unroll
      for (int qs = 0; qs < 4; qs++) {
        f32x4 s0 = zero4, s1 = zero4;
        __builtin_amdgcn_s_setprio(1);
        s0 = MFMA(ka0, qf0[qs], s0);
        s0 = MFMA(ka1, qf1[qs], s0);
        s1 = MFMA(kb0, qf0[qs], s1);
        s1 = MFMA(kb1, qf1[qs], s1);
        __builtin_amdgcn_s_setprio(0);
        float p0[4], p1[4], ls = 0.f;
#pragma unroll
        for (int r = 0; r < 4; r++) {
          p0[r] = __builtin_amdgcn_exp2f(s0[r] + RB);
          p1[r] = __builtin_amdgcn_exp2f(s1[r] + RB);
          ls += p0[r] + p1[r];
        }
        lsum[qs] += ls;
        u32x4 pw;
        pw[0] = pkbf(p0[1], p0[0]);
        pw[1] = pkbf(p0[3], p0[2]);
        pw[2] = pkbf(p1[1], p1[0]);
        pw[3] = pkbf(p1[3], p1[2]);
        bf16x8 pf = __builtin_bit_cast(bf16x8, pw);
        __builtin_amdgcn_s_setprio(1);
#pragma unroll
        for (int dt = 0; dt < 4; dt++)
          O[qs][dt] = MFMA(pf, vf[dt], O[qs][dt]);
        __builtin_amdgcn_s_setprio(0);
      }
    }
    __syncthreads();                     // all reads of buf[sel] done; buf[sel^1] landed
  }
#undef STAGE

  // epilogue: per-wave 64x64 bf16 transpose through (now free) LDS, then 16B/lane
  // stores -> full 128B lines per instruction.
  unsigned short* ow = (wv < 4) ? (Ks + wv * 4096) : (Vt + (wv - 4) * 4096);
#pragma unroll
  for (int qs = 0; qs < 4; qs++) {
    float ls = lsum[qs];
    ls += __shfl_xor(ls, 16);
    ls += __shfl_xor(ls, 32);
    float linv = 1.0f / ls;              // valid for query l16 in every lane
    float li[4];
#pragma unroll
    for (int r = 0; r < 4; r++) li[r] = __shfl(linv, quad * 4 + r);
#pragma unroll
    for (int dt = 0; dt < 4; dt++)
#pragma unroll
      for (int r = 0; r < 4; r++)
        ow[(qs * 16 + quad * 4 + r) * 64 + dt * 16 + l16] = f2bf(O[qs][dt][r] * li[r]);
  }
  __syncthreads();
  const size_t orow0 = (size_t)b * 4096 + n * 512 + wv * 64;
  const int rrow = lane >> 3, rch = lane & 7;
#pragma unroll
  for (int i = 0; i < 8; i++) {
    int row = i * 8 + rrow;
    u16x8 val = *(const u16x8*)(ow + row * 64 + rch * 8);
    *(u16x8*)(o + (orow0 + row) * 1024 + h * 64 + rch * 8) = val;
  }
}

// ---------------- output projection GEMM: same BK=64 + swizzle structure
__global__ __launch_bounds__(256) void out_gemm(const unsigned short* __restrict__ A,
                                                const unsigned short* __restrict__ wT,
                                                const float* __restrict__ bout,
                                                float* __restrict__ out) {
  __shared__ __align__(16) unsigned short As[128 * 64];
  __shared__ __align__(16) unsigned short Bs[128 * 64];
  const int tid = threadIdx.x;
  const int m0 = blockIdx.y * 128;
  const int n0 = blockIdx.x * 128;
  const int lane = tid & 63, wv = tid >> 6;
  const int wm = (wv >> 1) * 64, wn = (wv & 1) * 64;
  const int l16 = lane & 15, quad = lane >> 4;

  const int srow = lane >> 3;
  const int sc = ((lane & 7) ^ srow) * 8;
  const unsigned short* ga = A + ((size_t)(m0 + wv * 32 + srow)) * 1024 + sc;
  const unsigned short* gb = wT + ((size_t)(n0 + wv * 32 + srow)) * 1024 + sc;
  unsigned short* la = As + wv * 2048;
  unsigned short* lb = Bs + wv * 2048;
  const int xsw = (l16 & 7) * 8;

  const f32x4 zero4 = {0.f, 0.f, 0.f, 0.f};
  f32x4 acc[4][4];
#pragma unroll
  for (int i = 0; i < 4; i++)
#pragma unroll
    for (int j = 0; j < 4; j++) acc[i][j] = zero4;

  for (int k0 = 0; k0 < 1024; k0 += 64) {
    __syncthreads();
#pragma unroll
    for (int j = 0; j < 4; j++) {
      lds16(ga + j * 8 * 1024, la + j * 512);
      lds16(gb + j * 8 * 1024, lb + j * 512);
    }
    __syncthreads();
#pragma unroll
    for (int h = 0; h < 2; h++) {
      bf16x8 af[4], bfv[4];
#pragma unroll
      for (int i = 0; i < 4; i++)
        af[i] = *(const bf16x8*)(&As[(wm + i * 16 + l16) * 64 + (((h << 5) + quad * 8) ^ xsw)]);
#pragma unroll
      for (int j = 0; j < 4; j++)
        bfv[j] = *(const bf16x8*)(&Bs[(wn + j * 16 + l16) * 64 + (((h << 5) + quad * 8) ^ xsw)]);
#pragma unroll
      for (int i = 0; i < 4; i++)
#pragma unroll
        for (int j = 0; j < 4; j++)
          acc[i][j] = MFMA(af[i], bfv[j], acc[i][j]);
    }
    ga += 64;
    gb += 64;
  }

#pragma unroll
  for (int j = 0; j < 4; j++) {
    int col = n0 + wn + j * 16 + l16;
    float bias = bout[col];
#pragma unroll
    for (int i = 0; i < 4; i++) {
      int row = m0 + wm + i * 16 + quad * 4;
#pragma unroll
      for (int r = 0; r < 4; r++)
        out[(size_t)(row + r) * 1024 + col] = acc[i][j][r] + bias;
    }
  }
}

// ---------------- workspace layout (bytes); xbf aliases ows (dead until attn writes)
#define WQKVT_OFF 0u
#define WOUTT_OFF (WQKVT_OFF + 3072u * 1024u * 2u)          // 6291456
#define QWS_OFF   (WOUTT_OFF + 1024u * 1024u * 2u)          // 8388608
#define KVQ_SZ    (4u * 16u * 2304u * 64u * 2u)             // 18874368
#define KWS_OFF   (QWS_OFF + KVQ_SZ)
#define VWS_OFF   (KWS_OFF + KVQ_SZ)
#define OWS_OFF   (VWS_OFF + KVQ_SZ)                        // 65011712
#define XBF_OFF   OWS_OFF                                   // alias: 18.9MB <= 33.5MB
// total = OWS_OFF + 4*4096*1024*2 = 98,566,144 bytes

extern "C" void kernel_launch(void* const* d_in, const int* in_sizes, int n_in,
                              void* d_out, int out_size, void* d_ws, size_t ws_size,
                              hipStream_t stream) {
  const float* x     = (const float*)d_in[0];
  const float* w_qkv = (const float*)d_in[1];
  const float* b_qkv = (const float*)d_in[2];
  const float* w_out = (const float*)d_in[3];
  const float* b_out = (const float*)d_in[4];
  float* out = (float*)d_out;
  char* ws = (char*)d_ws;

  unsigned short* wqkvT = (unsigned short*)(ws + WQKVT_OFF);
  unsigned short* woutT = (unsigned short*)(ws + WOUTT_OFF);
  unsigned short* qws   = (unsigned short*)(ws + QWS_OFF);
  unsigned short* kws   = (unsigned short*)(ws + KWS_OFF);
  unsigned short* vws   = (unsigned short*)(ws + VWS_OFF);
  unsigned short* ows   = (unsigned short*)(ws + OWS_OFF);
  unsigned short* xbf   = (unsigned short*)(ws + XBF_OFF);

  preprocess<<<8704, 256, 0, stream>>>(x, xbf, w_qkv, wqkvT, w_out, woutT);

  qkv_gemm<<<dim3(24, 72), 256, 0, stream>>>(xbf, b_qkv, wqkvT, qws, kws, vws);

  // grid.x = h + 16*b (XCD = h%8 for all windows), grid.y = window
  attn_kernel<<<dim3(64, 8, 1), 512, 0, stream>>>(qws, kws, vws, ows);

  out_gemm<<<dim3(8, 128), 256, 0, stream>>>(ows, woutT, b_out, out);
}

// Round 4
// 369.109 us; speedup vs baseline: 1.3781x; 1.3781x over previous
//
#include <hip/hip_runtime.h>

// Problem constants: B=4, L=4096, C=1024, H=16, W=512, D=64, STRIDE=256
// Only windows 0..7 reach the output; q/k/v needed only for rows [0,2304) per batch.
#define LQ 2304

typedef __attribute__((ext_vector_type(8))) short bf16x8;
typedef __attribute__((ext_vector_type(8))) unsigned short u16x8;
typedef __attribute__((ext_vector_type(4))) float f32x4;
typedef __attribute__((ext_vector_type(4))) unsigned int u32x4;

#define MFMA(a, b, c) __builtin_amdgcn_mfma_f32_16x16x32_bf16((a), (b), (c), 0, 0, 0)
#define AS1 __attribute__((address_space(1)))
#define AS3 __attribute__((address_space(3)))

static __device__ __forceinline__ unsigned short f2bf(float f) {
  unsigned int u = __builtin_bit_cast(unsigned int, f);
  u += 0x7fffu + ((u >> 16) & 1u);
  return (unsigned short)(u >> 16);
}

// pack two positive f32 into bf16x2 by byte-perm truncation (caller pre-biases)
static __device__ __forceinline__ unsigned int pkbf(float hi, float lo) {
  return __builtin_amdgcn_perm(__builtin_bit_cast(unsigned int, hi),
                               __builtin_bit_cast(unsigned int, lo), 0x07060302u);
}

// async 16B/lane global->LDS; LDS image is wave-uniform base + lane*16 (no padding!)
static __device__ __forceinline__ void lds16(const unsigned short* g, unsigned short* l) {
  __builtin_amdgcn_global_load_lds((AS1 const unsigned int*)g, (AS3 unsigned int*)l, 16, 0, 0);
}

// ---------------- fused preprocessing: x fp32->bf16 + both weight transposes
// blocks [0,4608): conv_x; [4608,7680): w_qkv^T; [7680,8704): w_out^T
static __device__ __forceinline__ void transpose_body(const float* __restrict__ src,
                                                      unsigned short* __restrict__ dst,
                                                      int K, int N, int bx, int by, int tid,
                                                      float (*t)[33]) {
  int bn = bx * 32, bk = by * 32;
  int tx = tid & 31, ty = tid >> 5;
  for (int i = ty; i < 32; i += 8)
    t[i][tx] = src[(size_t)(bk + i) * N + bn + tx];
  __syncthreads();
  for (int i = ty; i < 32; i += 8)
    dst[(size_t)(bn + i) * K + bk + tx] = f2bf(t[tx][i]);
}

__global__ __launch_bounds__(256) void preprocess(const float* __restrict__ x,
                                                  unsigned short* __restrict__ xbf,
                                                  const float* __restrict__ wqkv,
                                                  unsigned short* __restrict__ wqkvT,
                                                  const float* __restrict__ wout,
                                                  unsigned short* __restrict__ woutT) {
  __shared__ float t[32][33];
  int bid = blockIdx.x, tid = threadIdx.x;
  if (bid < 4608) {
    int idx = bid * 256 + tid;          // [0, 1179648)
    int b = idx / 294912;               // 294912 = 2304*128
    int g = idx - b * 294912;
    int row = g >> 7, c8 = (g & 127) * 8;
    const float* src = x + ((size_t)b * 4096 + row) * 1024 + c8;
    float4 f0 = *(const float4*)src;
    float4 f1 = *(const float4*)(src + 4);
    u16x8 u;
    u[0] = f2bf(f0.x); u[1] = f2bf(f0.y); u[2] = f2bf(f0.z); u[3] = f2bf(f0.w);
    u[4] = f2bf(f1.x); u[5] = f2bf(f1.y); u[6] = f2bf(f1.z); u[7] = f2bf(f1.w);
    *(u16x8*)(xbf + ((size_t)b * 2304 + row) * 1024 + c8) = u;
  } else if (bid < 7680) {
    int tb = bid - 4608;
    transpose_body(wqkv, wqkvT, 1024, 3072, tb % 96, tb / 96, tid, t);
  } else {
    int tb = bid - 7680;
    transpose_body(wout, woutT, 1024, 1024, tb & 31, tb >> 5, tid, t);
  }
}

// ---------------- QKV projection GEMM: tile 128x128, BK=64, 256 threads = 2x2 waves.
// global_load_lds width-16 staging with 16B-granule XOR swizzle (chunk ^= row&7).
#define K2SCALE 0.18033688011112042f
__global__ __launch_bounds__(256) void qkv_gemm(const unsigned short* __restrict__ xbf,
                                                const float* __restrict__ bqkv,
                                                const unsigned short* __restrict__ wT,
                                                unsigned short* __restrict__ qws,
                                                unsigned short* __restrict__ kws,
                                                unsigned short* __restrict__ vws) {
  __shared__ __align__(16) unsigned short As[128 * 64];
  __shared__ __align__(16) unsigned short Bs[128 * 64];
  const int tid = threadIdx.x;
  const int mt = blockIdx.y;            // 0..71 : batch*18 + row-tile
  const int nt = blockIdx.x;            // 0..23
  const int bidx = mt / 18;
  const int l0 = (mt % 18) * 128;
  const int n0 = nt * 128;
  const int lane = tid & 63, wv = tid >> 6;
  const int wm = (wv >> 1) * 64, wn = (wv & 1) * 64;
  const int l16 = lane & 15, quad = lane >> 4;

  const int srow = lane >> 3;                 // 0..7
  const int sc = ((lane & 7) ^ srow) * 8;     // swizzled 16B chunk within the row
  const unsigned short* ga = xbf + ((size_t)(bidx * LQ + l0 + wv * 32 + srow)) * 1024 + sc;
  const unsigned short* gb = wT + ((size_t)(n0 + wv * 32 + srow)) * 1024 + sc;
  unsigned short* la = As + wv * 2048;
  unsigned short* lb = Bs + wv * 2048;
  const int xsw = (l16 & 7) * 8;              // reader-side swizzle key (row&7)*8

  const f32x4 zero4 = {0.f, 0.f, 0.f, 0.f};
  f32x4 acc[4][4];
#pragma unroll
  for (int i = 0; i < 4; i++)
#pragma unroll
    for (int j = 0; j < 4; j++) acc[i][j] = zero4;

  for (int k0 = 0; k0 < 1024; k0 += 64) {
    __syncthreads();
#pragma unroll
    for (int j = 0; j < 4; j++) {
      lds16(ga + j * 8 * 1024, la + j * 512);
      lds16(gb + j * 8 * 1024, lb + j * 512);
    }
    __syncthreads();
#pragma unroll
    for (int h = 0; h < 2; h++) {
      bf16x8 af[4], bfv[4];
#pragma unroll
      for (int i = 0; i < 4; i++)
        af[i] = *(const bf16x8*)(&As[(wm + i * 16 + l16) * 64 + (((h << 5) + quad * 8) ^ xsw)]);
#pragma unroll
      for (int j = 0; j < 4; j++)
        bfv[j] = *(const bf16x8*)(&Bs[(wn + j * 16 + l16) * 64 + (((h << 5) + quad * 8) ^ xsw)]);
#pragma unroll
      for (int i = 0; i < 4; i++)
#pragma unroll
        for (int j = 0; j < 4; j++)
          acc[i][j] = MFMA(af[i], bfv[j], acc[i][j]);
    }
    ga += 64;
    gb += 64;
  }

  // epilogue: scatter to q/k/v (B,H,LQ,64) with bias; q pre-scaled by K2SCALE
#pragma unroll
  for (int j = 0; j < 4; j++) {
    int col = n0 + wn + j * 16 + l16;   // [0,3072)
    int which = col >> 10;
    int hcol = (col >> 6) & 15;
    int dcol = col & 63;
    unsigned short* dst = which == 0 ? qws : (which == 1 ? kws : vws);
    float scale = which == 0 ? K2SCALE : 1.0f;
    float bias = bqkv[col];
    size_t cbase = ((size_t)bidx * 16 + hcol) * LQ * 64 + dcol;
#pragma unroll
    for (int i = 0; i < 4; i++) {
      int lrow = l0 + wm + i * 16 + quad * 4;
#pragma unroll
      for (int r = 0; r < 4; r++)
        dst[cbase + (size_t)(lrow + r) * 64] = f2bf((acc[i][j][r] + bias) * scale);
    }
  }
}

// ---------------- attention: one block per (head/batch hb, window n)
// grid.x = hb = h + 16*b so all 8 windows of one (b,h) land on ONE XCD
// (bid = hb + 64*n, XCD = bid%8 = hb%8) -> the 50%-overlapping K/V slices of
// adjacent windows become L2 hits instead of HBM re-fetches.
// Staging structure = round-0 verified (explicit loads, in-LDS V permute,
// single-buffer 35.8KB image) -- the DMA/double-buffer rewrite tripled HBM
// traffic (spill signature) and was reverted.
// LDS is a 64KB union: K/V staging image during the loop, 8x 64x64 per-wave
// transpose scratch afterwards so the output leaves as full 128B lines
// (u16x8/lane) instead of 2B scatter stores (which cost 4x write amplification).
#define KSTR 72
#define VSTRT 136

__global__ __launch_bounds__(512, 2) void attn_kernel(const unsigned short* __restrict__ q,
                                                      const unsigned short* __restrict__ k,
                                                      const unsigned short* __restrict__ v,
                                                      unsigned short* __restrict__ o) {
  __shared__ __align__(16) unsigned short lds[32768];   // 64 KB
  unsigned short* Ks = lds;                 // [128][KSTR]  (9216 shorts)
  unsigned short* Vt = lds + 128 * KSTR;    // [64][VSTRT]  (8704 shorts; 35840 B total)
  const int hb = blockIdx.x, n = blockIdx.y;
  const int h = hb & 15, b = hb >> 4;
  const size_t base = (((size_t)b * 16 + h) * LQ + n * 256) * 64;
  const unsigned short* qg = q + base;
  const unsigned short* kg = k + base;
  const unsigned short* vg = v + base;
  const int tid = threadIdx.x;
  const int lane = tid & 63, wv = tid >> 6;
  const int l16 = lane & 15, quad = lane >> 4;
  const f32x4 zero4 = {0.f, 0.f, 0.f, 0.f};
  const float RB = 0.002815015607053277f;  // log2(1 + 2^-9): centers perm-truncation

  bf16x8 qf0[4], qf1[4];
#pragma unroll
  for (int qs = 0; qs < 4; qs++) {
    int qrow = wv * 64 + qs * 16 + l16;
    qf0[qs] = *(const bf16x8*)(qg + (size_t)qrow * 64 + quad * 8);
    qf1[qs] = *(const bf16x8*)(qg + (size_t)qrow * 64 + quad * 8 + 32);
  }
  f32x4 O[4][4];
#pragma unroll
  for (int qs = 0; qs < 4; qs++)
#pragma unroll
    for (int dt = 0; dt < 4; dt++) O[qs][dt] = zero4;
  float lsum[4] = {0.f, 0.f, 0.f, 0.f};

  for (int kt = 0; kt < 4; kt++) {
    __syncthreads();                    // previous tile fully consumed
    // K tile: 128 keys x 64d, row stride 72 (conflict-free b128 reads & writes)
#pragma unroll
    for (int it = 0; it < 2; it++) {
      int i = it * 512 + tid;           // [0,1024)
      int key = i >> 3, part = i & 7;
      *(u16x8*)(&Ks[key * KSTR + part * 8]) =
          *(const u16x8*)(kg + (size_t)(kt * 128 + key) * 64 + part * 8);
    }
    // V tile: wave wv stages d-rows [8wv,8wv+8) -> consecutive permuted positions
    // within a row = 2-way bank aliasing (free).
#pragma unroll
    for (int it = 0; it < 2; it++) {
      int key = it * 64 + lane;         // [0,128)
      u16x8 raw = *(const u16x8*)(vg + (size_t)(kt * 128 + key) * 64 + wv * 8);
      // within-chunk perm: phys key = 32c + 16t + 4q + r -> pos = 32c + 8q + 4t + r
      int pos = (key & ~31) + ((key >> 2) & 3) * 8 + ((key >> 4) & 1) * 4 + (key & 3);
#pragma unroll
      for (int t = 0; t < 8; t++) Vt[(wv * 8 + t) * VSTRT + pos] = raw[t];
    }
    __syncthreads();

    for (int c = 0; c < 4; c++) {
      const unsigned short* kr0 = &Ks[(c * 32 + l16) * KSTR + quad * 8];
      bf16x8 ka0 = *(const bf16x8*)kr0;
      bf16x8 ka1 = *(const bf16x8*)(kr0 + 32);
      bf16x8 kb0 = *(const bf16x8*)(kr0 + 16 * KSTR);
      bf16x8 kb1 = *(const bf16x8*)(kr0 + 16 * KSTR + 32);
      bf16x8 vf[4];
#pragma unroll
      for (int dt = 0; dt < 4; dt++)
        vf[dt] = *(const bf16x8*)(&Vt[(dt * 16 + l16) * VSTRT + c * 32 + quad * 8]);
#pragma unroll
      for (int qs = 0; qs < 4; qs++) {
        f32x4 s0 = zero4, s1 = zero4;
        __builtin_amdgcn_s_setprio(1);
        s0 = MFMA(ka0, qf0[qs], s0);
        s0 = MFMA(ka1, qf1[qs], s0);
        s1 = MFMA(kb0, qf0[qs], s1);
        s1 = MFMA(kb1, qf1[qs], s1);
        __builtin_amdgcn_s_setprio(0);
        float p0[4], p1[4], ls = 0.f;
#pragma unroll
        for (int r = 0; r < 4; r++) {
          p0[r] = __builtin_amdgcn_exp2f(s0[r] + RB);
          p1[r] = __builtin_amdgcn_exp2f(s1[r] + RB);
          ls += p0[r] + p1[r];
        }
        lsum[qs] += ls;
        u32x4 pw;
        pw[0] = pkbf(p0[1], p0[0]);
        pw[1] = pkbf(p0[3], p0[2]);
        pw[2] = pkbf(p1[1], p1[0]);
        pw[3] = pkbf(p1[3], p1[2]);
        bf16x8 pf = __builtin_bit_cast(bf16x8, pw);
        __builtin_amdgcn_s_setprio(1);
#pragma unroll
        for (int dt = 0; dt < 4; dt++)
          O[qs][dt] = MFMA(pf, vf[dt], O[qs][dt]);
        __builtin_amdgcn_s_setprio(0);
      }
    }
  }

  // epilogue: per-wave 64x64 bf16 transpose through the (now free) 64KB LDS,
  // then 16B/lane stores -> full 128B-aligned segments per instruction.
  __syncthreads();                      // staging image no longer needed by anyone
  unsigned short* ow = lds + wv * 4096;
#pragma unroll
  for (int qs = 0; qs < 4; qs++) {
    float ls = lsum[qs];
    ls += __shfl_xor(ls, 16);
    ls += __shfl_xor(ls, 32);
    float linv = 1.0f / ls;              // valid for query l16 in every lane
    float li[4];
#pragma unroll
    for (int r = 0; r < 4; r++) li[r] = __shfl(linv, quad * 4 + r);
#pragma unroll
    for (int dt = 0; dt < 4; dt++)
#pragma unroll
      for (int r = 0; r < 4; r++)
        ow[(qs * 16 + quad * 4 + r) * 64 + dt * 16 + l16] = f2bf(O[qs][dt][r] * li[r]);
  }
  __syncthreads();
  const size_t orow0 = (size_t)b * 4096 + n * 512 + wv * 64;
  const int rrow = lane >> 3, rch = lane & 7;
#pragma unroll
  for (int i = 0; i < 8; i++) {
    int row = i * 8 + rrow;
    u16x8 val = *(const u16x8*)(ow + row * 64 + rch * 8);
    *(u16x8*)(o + (orow0 + row) * 1024 + h * 64 + rch * 8) = val;
  }
}

// ---------------- output projection GEMM: same BK=64 + swizzle structure
__global__ __launch_bounds__(256) void out_gemm(const unsigned short* __restrict__ A,
                                                const unsigned short* __restrict__ wT,
                                                const float* __restrict__ bout,
                                                float* __restrict__ out) {
  __shared__ __align__(16) unsigned short As[128 * 64];
  __shared__ __align__(16) unsigned short Bs[128 * 64];
  const int tid = threadIdx.x;
  const int m0 = blockIdx.y * 128;
  const int n0 = blockIdx.x * 128;
  const int lane = tid & 63, wv = tid >> 6;
  const int wm = (wv >> 1) * 64, wn = (wv & 1) * 64;
  const int l16 = lane & 15, quad = lane >> 4;

  const int srow = lane >> 3;
  const int sc = ((lane & 7) ^ srow) * 8;
  const unsigned short* ga = A + ((size_t)(m0 + wv * 32 + srow)) * 1024 + sc;
  const unsigned short* gb = wT + ((size_t)(n0 + wv * 32 + srow)) * 1024 + sc;
  unsigned short* la = As + wv * 2048;
  unsigned short* lb = Bs + wv * 2048;
  const int xsw = (l16 & 7) * 8;

  const f32x4 zero4 = {0.f, 0.f, 0.f, 0.f};
  f32x4 acc[4][4];
#pragma unroll
  for (int i = 0; i < 4; i++)
#pragma unroll
    for (int j = 0; j < 4; j++) acc[i][j] = zero4;

  for (int k0 = 0; k0 < 1024; k0 += 64) {
    __syncthreads();
#pragma unroll
    for (int j = 0; j < 4; j++) {
      lds16(ga + j * 8 * 1024, la + j * 512);
      lds16(gb + j * 8 * 1024, lb + j * 512);
    }
    __syncthreads();
#pragma unroll
    for (int h = 0; h < 2; h++) {
      bf16x8 af[4], bfv[4];
#pragma unroll
      for (int i = 0; i < 4; i++)
        af[i] = *(const bf16x8*)(&As[(wm + i * 16 + l16) * 64 + (((h << 5) + quad * 8) ^ xsw)]);
#pragma unroll
      for (int j = 0; j < 4; j++)
        bfv[j] = *(const bf16x8*)(&Bs[(wn + j * 16 + l16) * 64 + (((h << 5) + quad * 8) ^ xsw)]);
#pragma unroll
      for (int i = 0; i < 4; i++)
#pragma unroll
        for (int j = 0; j < 4; j++)
          acc[i][j] = MFMA(af[i], bfv[j], acc[i][j]);
    }
    ga += 64;
    gb += 64;
  }

#pragma unroll
  for (int j = 0; j < 4; j++) {
    int col = n0 + wn + j * 16 + l16;
    float bias = bout[col];
#pragma unroll
    for (int i = 0; i < 4; i++) {
      int row = m0 + wm + i * 16 + quad * 4;
#pragma unroll
      for (int r = 0; r < 4; r++)
        out[(size_t)(row + r) * 1024 + col] = acc[i][j][r] + bias;
    }
  }
}

// ---------------- workspace layout (bytes); xbf aliases ows (dead until attn writes)
#define WQKVT_OFF 0u
#define WOUTT_OFF (WQKVT_OFF + 3072u * 1024u * 2u)          // 6291456
#define QWS_OFF   (WOUTT_OFF + 1024u * 1024u * 2u)          // 8388608
#define KVQ_SZ    (4u * 16u * 2304u * 64u * 2u)             // 18874368
#define KWS_OFF   (QWS_OFF + KVQ_SZ)
#define VWS_OFF   (KWS_OFF + KVQ_SZ)
#define OWS_OFF   (VWS_OFF + KVQ_SZ)                        // 65011712
#define XBF_OFF   OWS_OFF                                   // alias: 18.9MB <= 33.5MB
// total = OWS_OFF + 4*4096*1024*2 = 98,566,144 bytes

extern "C" void kernel_launch(void* const* d_in, const int* in_sizes, int n_in,
                              void* d_out, int out_size, void* d_ws, size_t ws_size,
                              hipStream_t stream) {
  const float* x     = (const float*)d_in[0];
  const float* w_qkv = (const float*)d_in[1];
  const float* b_qkv = (const float*)d_in[2];
  const float* w_out = (const float*)d_in[3];
  const float* b_out = (const float*)d_in[4];
  float* out = (float*)d_out;
  char* ws = (char*)d_ws;

  unsigned short* wqkvT = (unsigned short*)(ws + WQKVT_OFF);
  unsigned short* woutT = (unsigned short*)(ws + WOUTT_OFF);
  unsigned short* qws   = (unsigned short*)(ws + QWS_OFF);
  unsigned short* kws   = (unsigned short*)(ws + KWS_OFF);
  unsigned short* vws   = (unsigned short*)(ws + VWS_OFF);
  unsigned short* ows   = (unsigned short*)(ws + OWS_OFF);
  unsigned short* xbf   = (unsigned short*)(ws + XBF_OFF);

  preprocess<<<8704, 256, 0, stream>>>(x, xbf, w_qkv, wqkvT, w_out, woutT);

  qkv_gemm<<<dim3(24, 72), 256, 0, stream>>>(xbf, b_qkv, wqkvT, qws, kws, vws);

  // grid.x = h + 16*b (XCD = hb%8 for all 8 windows of a (b,h)), grid.y = window
  attn_kernel<<<dim3(64, 8, 1), 512, 0, stream>>>(qws, kws, vws, ows);

  out_gemm<<<dim3(8, 128), 256, 0, stream>>>(ows, woutT, b_out, out);
}

// Round 5
// 328.112 us; speedup vs baseline: 1.5503x; 1.1249x over previous
//
#include <hip/hip_runtime.h>

// Problem constants: B=4, L=4096, C=1024, H=16, W=512, D=64, STRIDE=256
// Only windows 0..7 reach the output; q/k/v needed only for rows [0,2304) per batch.
#define LQ 2304

typedef __attribute__((ext_vector_type(8))) short bf16x8;
typedef __attribute__((ext_vector_type(8))) unsigned short u16x8;
typedef __attribute__((ext_vector_type(4))) float f32x4;
typedef __attribute__((ext_vector_type(4))) unsigned int u32x4;

#define MFMA(a, b, c) __builtin_amdgcn_mfma_f32_16x16x32_bf16((a), (b), (c), 0, 0, 0)
#define AS1 __attribute__((address_space(1)))
#define AS3 __attribute__((address_space(3)))

static __device__ __forceinline__ unsigned short f2bf(float f) {
  unsigned int u = __builtin_bit_cast(unsigned int, f);
  u += 0x7fffu + ((u >> 16) & 1u);
  return (unsigned short)(u >> 16);
}

// pack two positive f32 into bf16x2 by byte-perm truncation (caller pre-biases)
static __device__ __forceinline__ unsigned int pkbf(float hi, float lo) {
  return __builtin_amdgcn_perm(__builtin_bit_cast(unsigned int, hi),
                               __builtin_bit_cast(unsigned int, lo), 0x07060302u);
}

// async 16B/lane global->LDS; LDS image is wave-uniform base + lane*16 (no padding!)
static __device__ __forceinline__ void lds16(const unsigned short* g, unsigned short* l) {
  __builtin_amdgcn_global_load_lds((AS1 const unsigned int*)g, (AS3 unsigned int*)l, 16, 0, 0);
}

// ---------------- fused preprocessing: x fp32->bf16 + both weight transposes
// blocks [0,4608): conv_x; [4608,7680): w_qkv^T; [7680,8704): w_out^T
static __device__ __forceinline__ void transpose_body(const float* __restrict__ src,
                                                      unsigned short* __restrict__ dst,
                                                      int K, int N, int bx, int by, int tid,
                                                      float (*t)[33]) {
  int bn = bx * 32, bk = by * 32;
  int tx = tid & 31, ty = tid >> 5;
  for (int i = ty; i < 32; i += 8)
    t[i][tx] = src[(size_t)(bk + i) * N + bn + tx];
  __syncthreads();
  for (int i = ty; i < 32; i += 8)
    dst[(size_t)(bn + i) * K + bk + tx] = f2bf(t[tx][i]);
}

__global__ __launch_bounds__(256) void preprocess(const float* __restrict__ x,
                                                  unsigned short* __restrict__ xbf,
                                                  const float* __restrict__ wqkv,
                                                  unsigned short* __restrict__ wqkvT,
                                                  const float* __restrict__ wout,
                                                  unsigned short* __restrict__ woutT) {
  __shared__ float t[32][33];
  int bid = blockIdx.x, tid = threadIdx.x;
  if (bid < 4608) {
    int idx = bid * 256 + tid;          // [0, 1179648)
    int b = idx / 294912;               // 294912 = 2304*128
    int g = idx - b * 294912;
    int row = g >> 7, c8 = (g & 127) * 8;
    const float* src = x + ((size_t)b * 4096 + row) * 1024 + c8;
    float4 f0 = *(const float4*)src;
    float4 f1 = *(const float4*)(src + 4);
    u16x8 u;
    u[0] = f2bf(f0.x); u[1] = f2bf(f0.y); u[2] = f2bf(f0.z); u[3] = f2bf(f0.w);
    u[4] = f2bf(f1.x); u[5] = f2bf(f1.y); u[6] = f2bf(f1.z); u[7] = f2bf(f1.w);
    *(u16x8*)(xbf + ((size_t)b * 2304 + row) * 1024 + c8) = u;
  } else if (bid < 7680) {
    int tb = bid - 4608;
    transpose_body(wqkv, wqkvT, 1024, 3072, tb % 96, tb / 96, tid, t);
  } else {
    int tb = bid - 7680;
    transpose_body(wout, woutT, 1024, 1024, tb & 31, tb >> 5, tid, t);
  }
}

// ---------------- QKV projection GEMM: tile 128x128, BK=64, 256 threads = 2x2 waves.
// global_load_lds width-16 staging with 16B-granule XOR swizzle (chunk ^= row&7).
#define K2SCALE 0.18033688011112042f
__global__ __launch_bounds__(256) void qkv_gemm(const unsigned short* __restrict__ xbf,
                                                const float* __restrict__ bqkv,
                                                const unsigned short* __restrict__ wT,
                                                unsigned short* __restrict__ qws,
                                                unsigned short* __restrict__ kws,
                                                unsigned short* __restrict__ vws) {
  __shared__ __align__(16) unsigned short As[128 * 64];
  __shared__ __align__(16) unsigned short Bs[128 * 64];
  const int tid = threadIdx.x;
  const int mt = blockIdx.y;            // 0..71 : batch*18 + row-tile
  const int nt = blockIdx.x;            // 0..23
  const int bidx = mt / 18;
  const int l0 = (mt % 18) * 128;
  const int n0 = nt * 128;
  const int lane = tid & 63, wv = tid >> 6;
  const int wm = (wv >> 1) * 64, wn = (wv & 1) * 64;
  const int l16 = lane & 15, quad = lane >> 4;

  const int srow = lane >> 3;                 // 0..7
  const int sc = ((lane & 7) ^ srow) * 8;     // swizzled 16B chunk within the row
  const unsigned short* ga = xbf + ((size_t)(bidx * LQ + l0 + wv * 32 + srow)) * 1024 + sc;
  const unsigned short* gb = wT + ((size_t)(n0 + wv * 32 + srow)) * 1024 + sc;
  unsigned short* la = As + wv * 2048;
  unsigned short* lb = Bs + wv * 2048;
  const int xsw = (l16 & 7) * 8;              // reader-side swizzle key (row&7)*8

  const f32x4 zero4 = {0.f, 0.f, 0.f, 0.f};
  f32x4 acc[4][4];
#pragma unroll
  for (int i = 0; i < 4; i++)
#pragma unroll
    for (int j = 0; j < 4; j++) acc[i][j] = zero4;

  for (int k0 = 0; k0 < 1024; k0 += 64) {
    __syncthreads();
#pragma unroll
    for (int j = 0; j < 4; j++) {
      lds16(ga + j * 8 * 1024, la + j * 512);
      lds16(gb + j * 8 * 1024, lb + j * 512);
    }
    __syncthreads();
#pragma unroll
    for (int h = 0; h < 2; h++) {
      bf16x8 af[4], bfv[4];
#pragma unroll
      for (int i = 0; i < 4; i++)
        af[i] = *(const bf16x8*)(&As[(wm + i * 16 + l16) * 64 + (((h << 5) + quad * 8) ^ xsw)]);
#pragma unroll
      for (int j = 0; j < 4; j++)
        bfv[j] = *(const bf16x8*)(&Bs[(wn + j * 16 + l16) * 64 + (((h << 5) + quad * 8) ^ xsw)]);
#pragma unroll
      for (int i = 0; i < 4; i++)
#pragma unroll
        for (int j = 0; j < 4; j++)
          acc[i][j] = MFMA(af[i], bfv[j], acc[i][j]);
    }
    ga += 64;
    gb += 64;
  }

  // epilogue: scatter to q/k/v (B,H,LQ,64) with bias; q pre-scaled by K2SCALE
#pragma unroll
  for (int j = 0; j < 4; j++) {
    int col = n0 + wn + j * 16 + l16;   // [0,3072)
    int which = col >> 10;
    int hcol = (col >> 6) & 15;
    int dcol = col & 63;
    unsigned short* dst = which == 0 ? qws : (which == 1 ? kws : vws);
    float scale = which == 0 ? K2SCALE : 1.0f;
    float bias = bqkv[col];
    size_t cbase = ((size_t)bidx * 16 + hcol) * LQ * 64 + dcol;
#pragma unroll
    for (int i = 0; i < 4; i++) {
      int lrow = l0 + wm + i * 16 + quad * 4;
#pragma unroll
      for (int r = 0; r < 4; r++)
        dst[cbase + (size_t)(lrow + r) * 64] = f2bf((acc[i][j][r] + bias) * scale);
    }
  }
}

// ---------------- attention: one block per (head/batch hb, window n)
// grid.x = hb = h + 16*b so all 8 windows of one (b,h) land on ONE XCD
// (bid = hb + 64*n, XCD = bid%8 = hb%8) -> the 50%-overlapping K/V slices of
// adjacent windows become L2 hits instead of HBM re-fetches.
// Staging structure = round-0 verified (explicit loads, in-LDS V permute,
// single-buffer 35.8KB image). NO s_setprio anywhere: wrapping the MFMA
// clusters in setprio(1)/(0) acted as scheduling fences, blew past the
// 128-VGPR allocation and spilled ~115B/thread/iter to scratch (round-3/4
// counters: +110MB fetch, +120MB write, symmetric = spill signature).
// LDS is a 64KB union: K/V staging image during the loop, 8x 64x64 per-wave
// transpose scratch afterwards so the output leaves as full 128B lines
// (u16x8/lane) instead of 2B scatter stores (which cost 4x write amplification).
#define KSTR 72
#define VSTRT 136

__global__ __launch_bounds__(512, 2) void attn_kernel(const unsigned short* __restrict__ q,
                                                      const unsigned short* __restrict__ k,
                                                      const unsigned short* __restrict__ v,
                                                      unsigned short* __restrict__ o) {
  __shared__ __align__(16) unsigned short lds[32768];   // 64 KB
  unsigned short* Ks = lds;                 // [128][KSTR]  (9216 shorts)
  unsigned short* Vt = lds + 128 * KSTR;    // [64][VSTRT]  (8704 shorts; 35840 B total)
  const int hb = blockIdx.x, n = blockIdx.y;
  const int h = hb & 15, b = hb >> 4;
  const size_t base = (((size_t)b * 16 + h) * LQ + n * 256) * 64;
  const unsigned short* qg = q + base;
  const unsigned short* kg = k + base;
  const unsigned short* vg = v + base;
  const int tid = threadIdx.x;
  const int lane = tid & 63, wv = tid >> 6;
  const int l16 = lane & 15, quad = lane >> 4;
  const f32x4 zero4 = {0.f, 0.f, 0.f, 0.f};
  const float RB = 0.002815015607053277f;  // log2(1 + 2^-9): centers perm-truncation

  bf16x8 qf0[4], qf1[4];
#pragma unroll
  for (int qs = 0; qs < 4; qs++) {
    int qrow = wv * 64 + qs * 16 + l16;
    qf0[qs] = *(const bf16x8*)(qg + (size_t)qrow * 64 + quad * 8);
    qf1[qs] = *(const bf16x8*)(qg + (size_t)qrow * 64 + quad * 8 + 32);
  }
  f32x4 O[4][4];
#pragma unroll
  for (int qs = 0; qs < 4; qs++)
#pragma unroll
    for (int dt = 0; dt < 4; dt++) O[qs][dt] = zero4;
  float lsum[4] = {0.f, 0.f, 0.f, 0.f};

  for (int kt = 0; kt < 4; kt++) {
    __syncthreads();                    // previous tile fully consumed
    // K tile: 128 keys x 64d, row stride 72 (conflict-free b128 reads & writes)
#pragma unroll
    for (int it = 0; it < 2; it++) {
      int i = it * 512 + tid;           // [0,1024)
      int key = i >> 3, part = i & 7;
      *(u16x8*)(&Ks[key * KSTR + part * 8]) =
          *(const u16x8*)(kg + (size_t)(kt * 128 + key) * 64 + part * 8);
    }
    // V tile: wave wv stages d-rows [8wv,8wv+8) -> consecutive permuted positions
    // within a row = 2-way bank aliasing (free).
#pragma unroll
    for (int it = 0; it < 2; it++) {
      int key = it * 64 + lane;         // [0,128)
      u16x8 raw = *(const u16x8*)(vg + (size_t)(kt * 128 + key) * 64 + wv * 8);
      // within-chunk perm: phys key = 32c + 16t + 4q + r -> pos = 32c + 8q + 4t + r
      int pos = (key & ~31) + ((key >> 2) & 3) * 8 + ((key >> 4) & 1) * 4 + (key & 3);
#pragma unroll
      for (int t = 0; t < 8; t++) Vt[(wv * 8 + t) * VSTRT + pos] = raw[t];
    }
    __syncthreads();

    for (int c = 0; c < 4; c++) {
      const unsigned short* kr0 = &Ks[(c * 32 + l16) * KSTR + quad * 8];
      bf16x8 ka0 = *(const bf16x8*)kr0;
      bf16x8 ka1 = *(const bf16x8*)(kr0 + 32);
      bf16x8 kb0 = *(const bf16x8*)(kr0 + 16 * KSTR);
      bf16x8 kb1 = *(const bf16x8*)(kr0 + 16 * KSTR + 32);
      bf16x8 vf[4];
#pragma unroll
      for (int dt = 0; dt < 4; dt++)
        vf[dt] = *(const bf16x8*)(&Vt[(dt * 16 + l16) * VSTRT + c * 32 + quad * 8]);
#pragma unroll
      for (int qs = 0; qs < 4; qs++) {
        f32x4 s0 = zero4, s1 = zero4;
        s0 = MFMA(ka0, qf0[qs], s0);
        s0 = MFMA(ka1, qf1[qs], s0);
        s1 = MFMA(kb0, qf0[qs], s1);
        s1 = MFMA(kb1, qf1[qs], s1);
        float p0[4], p1[4], ls = 0.f;
#pragma unroll
        for (int r = 0; r < 4; r++) {
          p0[r] = __builtin_amdgcn_exp2f(s0[r] + RB);
          p1[r] = __builtin_amdgcn_exp2f(s1[r] + RB);
          ls += p0[r] + p1[r];
        }
        lsum[qs] += ls;
        u32x4 pw;
        pw[0] = pkbf(p0[1], p0[0]);
        pw[1] = pkbf(p0[3], p0[2]);
        pw[2] = pkbf(p1[1], p1[0]);
        pw[3] = pkbf(p1[3], p1[2]);
        bf16x8 pf = __builtin_bit_cast(bf16x8, pw);
#pragma unroll
        for (int dt = 0; dt < 4; dt++)
          O[qs][dt] = MFMA(pf, vf[dt], O[qs][dt]);
      }
    }
  }

  // epilogue: per-wave 64x64 bf16 transpose through the (now free) 64KB LDS,
  // then 16B/lane stores -> full 128B-aligned segments per instruction.
  __syncthreads();                      // staging image no longer needed by anyone
  unsigned short* ow = lds + wv * 4096;
#pragma unroll
  for (int qs = 0; qs < 4; qs++) {
    float ls = lsum[qs];
    ls += __shfl_xor(ls, 16);
    ls += __shfl_xor(ls, 32);
    float linv = 1.0f / ls;              // valid for query l16 in every lane
    float li[4];
#pragma unroll
    for (int r = 0; r < 4; r++) li[r] = __shfl(linv, quad * 4 + r);
#pragma unroll
    for (int dt = 0; dt < 4; dt++)
#pragma unroll
      for (int r = 0; r < 4; r++)
        ow[(qs * 16 + quad * 4 + r) * 64 + dt * 16 + l16] = f2bf(O[qs][dt][r] * li[r]);
  }
  __syncthreads();
  const size_t orow0 = (size_t)b * 4096 + n * 512 + wv * 64;
  const int rrow = lane >> 3, rch = lane & 7;
#pragma unroll
  for (int i = 0; i < 8; i++) {
    int row = i * 8 + rrow;
    u16x8 val = *(const u16x8*)(ow + row * 64 + rch * 8);
    *(u16x8*)(o + (orow0 + row) * 1024 + h * 64 + rch * 8) = val;
  }
}

// ---------------- output projection GEMM: same BK=64 + swizzle structure
__global__ __launch_bounds__(256) void out_gemm(const unsigned short* __restrict__ A,
                                                const unsigned short* __restrict__ wT,
                                                const float* __restrict__ bout,
                                                float* __restrict__ out) {
  __shared__ __align__(16) unsigned short As[128 * 64];
  __shared__ __align__(16) unsigned short Bs[128 * 64];
  const int tid = threadIdx.x;
  const int m0 = blockIdx.y * 128;
  const int n0 = blockIdx.x * 128;
  const int lane = tid & 63, wv = tid >> 6;
  const int wm = (wv >> 1) * 64, wn = (wv & 1) * 64;
  const int l16 = lane & 15, quad = lane >> 4;

  const int srow = lane >> 3;
  const int sc = ((lane & 7) ^ srow) * 8;
  const unsigned short* ga = A + ((size_t)(m0 + wv * 32 + srow)) * 1024 + sc;
  const unsigned short* gb = wT + ((size_t)(n0 + wv * 32 + srow)) * 1024 + sc;
  unsigned short* la = As + wv * 2048;
  unsigned short* lb = Bs + wv * 2048;
  const int xsw = (l16 & 7) * 8;

  const f32x4 zero4 = {0.f, 0.f, 0.f, 0.f};
  f32x4 acc[4][4];
#pragma unroll
  for (int i = 0; i < 4; i++)
#pragma unroll
    for (int j = 0; j < 4; j++) acc[i][j] = zero4;

  for (int k0 = 0; k0 < 1024; k0 += 64) {
    __syncthreads();
#pragma unroll
    for (int j = 0; j < 4; j++) {
      lds16(ga + j * 8 * 1024, la + j * 512);
      lds16(gb + j * 8 * 1024, lb + j * 512);
    }
    __syncthreads();
#pragma unroll
    for (int h = 0; h < 2; h++) {
      bf16x8 af[4], bfv[4];
#pragma unroll
      for (int i = 0; i < 4; i++)
        af[i] = *(const bf16x8*)(&As[(wm + i * 16 + l16) * 64 + (((h << 5) + quad * 8) ^ xsw)]);
#pragma unroll
      for (int j = 0; j < 4; j++)
        bfv[j] = *(const bf16x8*)(&Bs[(wn + j * 16 + l16) * 64 + (((h << 5) + quad * 8) ^ xsw)]);
#pragma unroll
      for (int i = 0; i < 4; i++)
#pragma unroll
        for (int j = 0; j < 4; j++)
          acc[i][j] = MFMA(af[i], bfv[j], acc[i][j]);
    }
    ga += 64;
    gb += 64;
  }

#pragma unroll
  for (int j = 0; j < 4; j++) {
    int col = n0 + wn + j * 16 + l16;
    float bias = bout[col];
#pragma unroll
    for (int i = 0; i < 4; i++) {
      int row = m0 + wm + i * 16 + quad * 4;
#pragma unroll
      for (int r = 0; r < 4; r++)
        out[(size_t)(row + r) * 1024 + col] = acc[i][j][r] + bias;
    }
  }
}

// ---------------- workspace layout (bytes); xbf aliases ows (dead until attn writes)
#define WQKVT_OFF 0u
#define WOUTT_OFF (WQKVT_OFF + 3072u * 1024u * 2u)          // 6291456
#define QWS_OFF   (WOUTT_OFF + 1024u * 1024u * 2u)          // 8388608
#define KVQ_SZ    (4u * 16u * 2304u * 64u * 2u)             // 18874368
#define KWS_OFF   (QWS_OFF + KVQ_SZ)
#define VWS_OFF   (KWS_OFF + KVQ_SZ)
#define OWS_OFF   (VWS_OFF + KVQ_SZ)                        // 65011712
#define XBF_OFF   OWS_OFF                                   // alias: 18.9MB <= 33.5MB
// total = OWS_OFF + 4*4096*1024*2 = 98,566,144 bytes

extern "C" void kernel_launch(void* const* d_in, const int* in_sizes, int n_in,
                              void* d_out, int out_size, void* d_ws, size_t ws_size,
                              hipStream_t stream) {
  const float* x     = (const float*)d_in[0];
  const float* w_qkv = (const float*)d_in[1];
  const float* b_qkv = (const float*)d_in[2];
  const float* w_out = (const float*)d_in[3];
  const float* b_out = (const float*)d_in[4];
  float* out = (float*)d_out;
  char* ws = (char*)d_ws;

  unsigned short* wqkvT = (unsigned short*)(ws + WQKVT_OFF);
  unsigned short* woutT = (unsigned short*)(ws + WOUTT_OFF);
  unsigned short* qws   = (unsigned short*)(ws + QWS_OFF);
  unsigned short* kws   = (unsigned short*)(ws + KWS_OFF);
  unsigned short* vws   = (unsigned short*)(ws + VWS_OFF);
  unsigned short* ows   = (unsigned short*)(ws + OWS_OFF);
  unsigned short* xbf   = (unsigned short*)(ws + XBF_OFF);

  preprocess<<<8704, 256, 0, stream>>>(x, xbf, w_qkv, wqkvT, w_out, woutT);

  qkv_gemm<<<dim3(24, 72), 256, 0, stream>>>(xbf, b_qkv, wqkvT, qws, kws, vws);

  // grid.x = h + 16*b (XCD = hb%8 for all 8 windows of a (b,h)), grid.y = window
  attn_kernel<<<dim3(64, 8, 1), 512, 0, stream>>>(qws, kws, vws, ows);

  out_gemm<<<dim3(8, 128), 256, 0, stream>>>(ows, woutT, b_out, out);
}